// Round 2
// baseline (137.495 us; speedup 1.0000x reference)
//
#include <hip/hip_runtime.h>

// SoftFAPELoss: B=8, N=M=4096, D=3.
// Two kernels:
//  pre_kernel: transform both clouds, pre-scale by c = log2(e)/T:
//     Yt4[b,m] = (-2c*y0, -2c*y1, -2c*y2, c*|y|^2)   (transformed X_true)
//     P4 [b,n] = ( p0,     p1,     p2,    c*|p|^2)   (transformed X_pred)
//  main_kernel: block = 16 waves; block owns 64 rows (lane == row),
//     wave w owns M-chunk [w*256, w*256+256). q is wave-uniform -> scalar
//     loads; p per-lane. dc = c*|p-q|^2 via 3 fma + 1 add. Single unshifted
//     softmax pass (args <= 0, no overflow); rare underflow rows repaired
//     with a block-uniform shifted re-pass. LDS only for the 16-way merge.

#define B_    8
#define N_    4096
#define M_    4096
#define NWAVE 16
#define BLOCK (NWAVE * 64)
#define CHUNK (M_ / NWAVE)          // 256 points per wave
#define LOG2E 1.4426950408889634f
#define LN2   0.6931471805599453f

__global__ __launch_bounds__(256) void pre_kernel(
    const float* __restrict__ X_pred, const float* __restrict__ X_true,
    const float* __restrict__ R_pred, const float* __restrict__ t_pred,
    const float* __restrict__ R_true, const float* __restrict__ t_true,
    const float* __restrict__ temp,
    float4* __restrict__ Yt4, float4* __restrict__ P4)
{
    const int i     = blockIdx.x * 256 + threadIdx.x;   // 0..32767
    const int which = blockIdx.y;                        // 0 = true, 1 = pred
    const int b     = i >> 12;

    const float c = LOG2E / temp[0];

    const float* R = (which ? R_pred : R_true) + b * 9;
    const float* t = (which ? t_pred : t_true) + b * 3;
    const float* X = (which ? X_pred : X_true) + (size_t)i * 3;

    const float x = X[0], y = X[1], z = X[2];
    const float y0 = fmaf(R[0], x, fmaf(R[1], y, fmaf(R[2], z, t[0])));
    const float y1 = fmaf(R[3], x, fmaf(R[4], y, fmaf(R[5], z, t[1])));
    const float y2 = fmaf(R[6], x, fmaf(R[7], y, fmaf(R[8], z, t[2])));
    const float nn = fmaf(y0, y0, fmaf(y1, y1, y2 * y2));

    if (which == 0) {
        const float m2c = -2.0f * c;
        Yt4[i] = make_float4(m2c * y0, m2c * y1, m2c * y2, c * nn);
    } else {
        P4[i] = make_float4(y0, y1, y2, c * nn);
    }
}

__global__ __launch_bounds__(BLOCK) void main_kernel(
    const float4* __restrict__ Yt4, const float4* __restrict__ P4,
    const float* __restrict__ temp, float* __restrict__ out)
{
    __shared__ float Lp[NWAVE][64];
    __shared__ float Sp[NWAVE][64];
    __shared__ float Mp[NWAVE][64];

    const int tid  = threadIdx.x;
    const int wave = tid >> 6;
    const int lane = tid & 63;
    const int b    = blockIdx.x >> 6;   // 64 row-groups per batch
    const int rg   = blockIdx.x & 63;

    // my row's record (lane == row within the 64-row group)
    const float4 p = P4[(b << 12) + (rg << 6) + lane];

    // wave-uniform chunk base -> scalar loads of q
    const int base = __builtin_amdgcn_readfirstlane((b << 12) + wave * CHUNK);
    const float4* __restrict__ Yq = Yt4 + base;

    float L = 0.0f, S = 0.0f, mind = 3.0e38f;
    #pragma unroll 8
    for (int k = 0; k < CHUNK; ++k) {
        const float4 q = Yq[k];
        const float dc = fmaf(q.x, p.x, fmaf(q.y, p.y, fmaf(q.z, p.z, q.w))) + p.w;
        mind = fminf(mind, dc);
        const float w = __builtin_amdgcn_exp2f(-dc);   // arg <= ~0: never overflows
        L += w;
        S = fmaf(w, dc, S);
    }

    Lp[wave][lane] = L;
    Sp[wave][lane] = S;
    Mp[wave][lane] = mind;
    __syncthreads();

    // every wave redundantly merges the 16 chunk-partials for row = lane
    float Lr = 0.0f, Sr = 0.0f, mr = 3.0e38f;
    #pragma unroll
    for (int w2 = 0; w2 < NWAVE; ++w2) {
        Lr += Lp[w2][lane];
        Sr += Sp[w2][lane];
        mr  = fminf(mr, Mp[w2][lane]);
    }

    // rare repair: some row's denominator fully underflowed (min dist^2 > ~10).
    // Condition is identical in every wave -> block-uniform branch.
    if (__ballot(Lr < 1e-30f)) {
        __syncthreads();   // everyone done reading partials
        float L2 = 0.0f, S2 = 0.0f;
        const float sh = mr;   // this lane's row min (exact, merged)
        #pragma unroll 8
        for (int k = 0; k < CHUNK; ++k) {
            const float4 q = Yq[k];
            const float dc = fmaf(q.x, p.x, fmaf(q.y, p.y, fmaf(q.z, p.z, q.w))) + p.w;
            const float w = __builtin_amdgcn_exp2f(sh - dc);  // <= 1, min pair -> 1
            L2 += w;
            S2 = fmaf(w, dc, S2);
        }
        Lp[wave][lane] = L2;
        Sp[wave][lane] = S2;
        __syncthreads();
        Lr = 0.0f; Sr = 0.0f;
        #pragma unroll
        for (int w2 = 0; w2 < NWAVE; ++w2) {
            Lr += Lp[w2][lane];
            Sr += Sp[w2][lane];
        }
    }

    if (wave == 0) {
        float wd = Sr / Lr;                    // = c * weighted_distance(row)
        wd += __shfl_xor(wd, 1);
        wd += __shfl_xor(wd, 2);
        wd += __shfl_xor(wd, 4);
        wd += __shfl_xor(wd, 8);
        wd += __shfl_xor(wd, 16);
        wd += __shfl_xor(wd, 32);
        if (lane == 0) {
            // unscale by 1/c = T*ln2, then mean over B*N rows
            const float scale = temp[0] * LN2 / ((float)B_ * (float)N_);
            atomicAdd(out, wd * scale);
        }
    }
}

extern "C" void kernel_launch(void* const* d_in, const int* in_sizes, int n_in,
                              void* d_out, int out_size, void* d_ws, size_t ws_size,
                              hipStream_t stream) {
    const float* X_pred = (const float*)d_in[0];
    const float* X_true = (const float*)d_in[1];
    const float* R_pred = (const float*)d_in[2];
    const float* t_pred = (const float*)d_in[3];
    const float* R_true = (const float*)d_in[4];
    const float* t_true = (const float*)d_in[5];
    const float* temp   = (const float*)d_in[6];
    float* out = (float*)d_out;

    float4* Yt4 = (float4*)d_ws;                 // B*M float4 = 512 KB
    float4* P4  = Yt4 + (size_t)B_ * M_;         // B*N float4 = 512 KB

    hipMemsetAsync(out, 0, sizeof(float), stream);

    pre_kernel<<<dim3((B_ * M_) / 256, 2), 256, 0, stream>>>(
        X_pred, X_true, R_pred, t_pred, R_true, t_true, temp, Yt4, P4);

    main_kernel<<<dim3(B_ * (N_ / 64)), BLOCK, 0, stream>>>(Yt4, P4, temp, out);
}

// Round 3
// 128.255 us; speedup vs baseline: 1.0720x; 1.0720x over previous
//
#include <hip/hip_runtime.h>

// SoftFAPELoss: B=8, N=M=4096, D=3. Single fused kernel.
// Grid = 256 blocks (1 per CU), block = 1024 thr = 16 waves.
// Block owns 128 rows of one batch (lane l -> rows 2l, 2l+1; R=2 per lane).
// The batch's 4096 X_true points are transformed+prescaled into LDS in two
// 2048-point stages (32 KB); wave w processes its private 128-q slice per
// stage via ds_read_b128 broadcast (all lanes same address -> 16 B return,
// 0 bank conflicts). Per pair: dc = c*|p-q|^2 via 3 fma + 1 add on the
// expanded square; w = exp2(-dc) (arg <= 0, no overflow); 16 per-row chunk
// partials merged through LDS. Rare full-underflow rows repaired by a cold
// block-uniform shifted re-pass.

#define B_    8
#define N_    4096
#define M_    4096
#define NWAVE 16
#define BLOCK (NWAVE * 64)       // 1024
#define ROWS  128                // rows per block (2 per lane)
#define HALF  2048               // q points per LDS stage
#define WCH   (HALF / NWAVE)     // 128 q per wave per stage
#define LOG2E 1.4426950408889634f
#define LN2   0.6931471805599453f

__global__ __launch_bounds__(BLOCK) void softfape_kernel(
    const float* __restrict__ X_pred, const float* __restrict__ X_true,
    const float* __restrict__ R_pred, const float* __restrict__ t_pred,
    const float* __restrict__ R_true, const float* __restrict__ t_true,
    const float* __restrict__ temp, float* __restrict__ out)
{
    __shared__ float4 Q[HALF];               // 32 KB
    __shared__ float  Lp[NWAVE][ROWS];       // 8 KB
    __shared__ float  Sp[NWAVE][ROWS];       // 8 KB
    __shared__ float  rowtmp[ROWS];
    __shared__ int    badflag;

    const int tid  = threadIdx.x;
    const int wave = tid >> 6;
    const int lane = tid & 63;
    const int b    = blockIdx.x >> 5;        // batch
    const int rg   = blockIdx.x & 31;        // row-group (32 x 128 rows = N)

    const float T   = temp[0];
    const float c   = LOG2E / T;
    const float m2c = -2.0f * c;

    if (tid == 0) badflag = 0;

    // true-side transform constants (uniform -> SGPRs)
    const float g00 = R_true[b*9+0], g01 = R_true[b*9+1], g02 = R_true[b*9+2];
    const float g10 = R_true[b*9+3], g11 = R_true[b*9+4], g12 = R_true[b*9+5];
    const float g20 = R_true[b*9+6], g21 = R_true[b*9+7], g22 = R_true[b*9+8];
    const float u0  = t_true[b*3+0], u1 = t_true[b*3+1], u2 = t_true[b*3+2];

    // ---- my 2 rows: transformed pred points + prescaled squared norms ----
    float p0x, p0y, p0z, pw0, p1x, p1y, p1z, pw1;
    {
        const int n0 = rg * ROWS + 2 * lane;
        const float2* xp = (const float2*)(X_pred + ((size_t)b * N_ + n0) * 3);
        const float2 a0 = xp[0], a1 = xp[1], a2 = xp[2];
        const float h00 = R_pred[b*9+0], h01 = R_pred[b*9+1], h02 = R_pred[b*9+2];
        const float h10 = R_pred[b*9+3], h11 = R_pred[b*9+4], h12 = R_pred[b*9+5];
        const float h20 = R_pred[b*9+6], h21 = R_pred[b*9+7], h22 = R_pred[b*9+8];
        const float v0 = t_pred[b*3+0], v1 = t_pred[b*3+1], v2 = t_pred[b*3+2];
        // row 0: (a0.x, a0.y, a1.x)
        p0x = fmaf(h00, a0.x, fmaf(h01, a0.y, fmaf(h02, a1.x, v0)));
        p0y = fmaf(h10, a0.x, fmaf(h11, a0.y, fmaf(h12, a1.x, v1)));
        p0z = fmaf(h20, a0.x, fmaf(h21, a0.y, fmaf(h22, a1.x, v2)));
        pw0 = c * fmaf(p0x, p0x, fmaf(p0y, p0y, p0z * p0z));
        // row 1: (a1.y, a2.x, a2.y)
        p1x = fmaf(h00, a1.y, fmaf(h01, a2.x, fmaf(h02, a2.y, v0)));
        p1y = fmaf(h10, a1.y, fmaf(h11, a2.x, fmaf(h12, a2.y, v1)));
        p1z = fmaf(h20, a1.y, fmaf(h21, a2.x, fmaf(h22, a2.y, v2)));
        pw1 = c * fmaf(p1x, p1x, fmaf(p1y, p1y, p1z * p1z));
    }

    // stage 2048 transformed true-points (half s) into Q; each thread does 2
    auto stage = [&](int s) {
        const float2* xt = (const float2*)(X_true + (size_t)b * M_ * 3
                                           + (size_t)s * HALF * 3);
        const float2 f0 = xt[3*tid+0], f1 = xt[3*tid+1], f2 = xt[3*tid+2];
        {
            const float y0 = fmaf(g00, f0.x, fmaf(g01, f0.y, fmaf(g02, f1.x, u0)));
            const float y1 = fmaf(g10, f0.x, fmaf(g11, f0.y, fmaf(g12, f1.x, u1)));
            const float y2 = fmaf(g20, f0.x, fmaf(g21, f0.y, fmaf(g22, f1.x, u2)));
            const float nn = fmaf(y0, y0, fmaf(y1, y1, y2 * y2));
            Q[2*tid]   = make_float4(m2c*y0, m2c*y1, m2c*y2, c*nn);
        }
        {
            const float y0 = fmaf(g00, f1.y, fmaf(g01, f2.x, fmaf(g02, f2.y, u0)));
            const float y1 = fmaf(g10, f1.y, fmaf(g11, f2.x, fmaf(g12, f2.y, u1)));
            const float y2 = fmaf(g20, f1.y, fmaf(g21, f2.x, fmaf(g22, f2.y, u2)));
            const float nn = fmaf(y0, y0, fmaf(y1, y1, y2 * y2));
            Q[2*tid+1] = make_float4(m2c*y0, m2c*y1, m2c*y2, c*nn);
        }
    };

    // ---- main pass: unshifted softmax accumulation (args <= ~0) ----
    float L0 = 0.0f, S0 = 0.0f, L1 = 0.0f, S1 = 0.0f;
    for (int s = 0; s < 2; ++s) {
        __syncthreads();
        stage(s);
        __syncthreads();
        const float4* __restrict__ Qc = Q + wave * WCH;
        #pragma unroll 4
        for (int k = 0; k < WCH; ++k) {
            const float4 q = Qc[k];    // ds_read_b128 broadcast (wave-uniform)
            const float A0 = fmaf(q.x, p0x, fmaf(q.y, p0y, fmaf(q.z, p0z, q.w)));
            const float d0 = A0 + pw0;
            const float w0 = __builtin_amdgcn_exp2f(-d0);
            L0 += w0;  S0 = fmaf(w0, d0, S0);
            const float A1 = fmaf(q.x, p1x, fmaf(q.y, p1y, fmaf(q.z, p1z, q.w)));
            const float d1 = A1 + pw1;
            const float w1 = __builtin_amdgcn_exp2f(-d1);
            L1 += w1;  S1 = fmaf(w1, d1, S1);
        }
    }
    Lp[wave][2*lane] = L0;  Lp[wave][2*lane+1] = L1;
    Sp[wave][2*lane] = S0;  Sp[wave][2*lane+1] = S1;
    __syncthreads();

    // ---- merge 16 chunk-partials per row (threads 0..127) ----
    float wd = 0.0f;
    if (tid < ROWS) {
        float Lr = 0.0f, Sr = 0.0f;
        #pragma unroll
        for (int w2 = 0; w2 < NWAVE; ++w2) { Lr += Lp[w2][tid]; Sr += Sp[w2][tid]; }
        if (Lr < 1e-37f) badflag = 1;     // benign same-value race
        wd = Sr / Lr;
    }
    __syncthreads();

    // ---- cold repair: some row's denominator fully underflowed ----
    if (badflag) {
        // pass A: per-row chunk minima
        float m0 = 3.0e38f, m1 = 3.0e38f;
        for (int s = 0; s < 2; ++s) {
            __syncthreads();
            stage(s);
            __syncthreads();
            const float4* __restrict__ Qc = Q + wave * WCH;
            for (int k = 0; k < WCH; ++k) {
                const float4 q = Qc[k];
                const float d0 = fmaf(q.x, p0x, fmaf(q.y, p0y, fmaf(q.z, p0z, q.w))) + pw0;
                const float d1 = fmaf(q.x, p1x, fmaf(q.y, p1y, fmaf(q.z, p1z, q.w))) + pw1;
                m0 = fminf(m0, d0);  m1 = fminf(m1, d1);
            }
        }
        Lp[wave][2*lane] = m0;  Lp[wave][2*lane+1] = m1;
        __syncthreads();
        if (tid < ROWS) {
            float mr = 3.0e38f;
            #pragma unroll
            for (int w2 = 0; w2 < NWAVE; ++w2) mr = fminf(mr, Lp[w2][tid]);
            rowtmp[tid] = mr;
        }
        __syncthreads();
        const float sh0 = rowtmp[2*lane], sh1 = rowtmp[2*lane+1];
        // pass B: shifted accumulation (min pair -> weight 1)
        L0 = S0 = L1 = S1 = 0.0f;
        for (int s = 0; s < 2; ++s) {
            __syncthreads();
            stage(s);
            __syncthreads();
            const float4* __restrict__ Qc = Q + wave * WCH;
            for (int k = 0; k < WCH; ++k) {
                const float4 q = Qc[k];
                const float d0 = fmaf(q.x, p0x, fmaf(q.y, p0y, fmaf(q.z, p0z, q.w))) + pw0;
                const float w0 = __builtin_amdgcn_exp2f(sh0 - d0);
                L0 += w0;  S0 = fmaf(w0, d0, S0);
                const float d1 = fmaf(q.x, p1x, fmaf(q.y, p1y, fmaf(q.z, p1z, q.w))) + pw1;
                const float w1 = __builtin_amdgcn_exp2f(sh1 - d1);
                L1 += w1;  S1 = fmaf(w1, d1, S1);
            }
        }
        Lp[wave][2*lane] = L0;  Lp[wave][2*lane+1] = L1;
        Sp[wave][2*lane] = S0;  Sp[wave][2*lane+1] = S1;
        __syncthreads();
        if (tid < ROWS) {
            float Lr = 0.0f, Sr = 0.0f;
            #pragma unroll
            for (int w2 = 0; w2 < NWAVE; ++w2) { Lr += Lp[w2][tid]; Sr += Sp[w2][tid]; }
            wd = Sr / Lr;
        }
        __syncthreads();
    }

    // ---- block reduction of 128 row results, one atomic per block ----
    if (tid < ROWS) rowtmp[tid] = wd;
    __syncthreads();
    if (wave == 0) {
        float v = rowtmp[lane] + rowtmp[64 + lane];
        v += __shfl_xor(v, 1);
        v += __shfl_xor(v, 2);
        v += __shfl_xor(v, 4);
        v += __shfl_xor(v, 8);
        v += __shfl_xor(v, 16);
        v += __shfl_xor(v, 32);
        if (lane == 0) {
            // wd values are c * weighted_distance; unscale by 1/c = T*ln2
            const float scale = T * LN2 / ((float)B_ * (float)N_);
            atomicAdd(out, v * scale);
        }
    }
}

extern "C" void kernel_launch(void* const* d_in, const int* in_sizes, int n_in,
                              void* d_out, int out_size, void* d_ws, size_t ws_size,
                              hipStream_t stream) {
    const float* X_pred = (const float*)d_in[0];
    const float* X_true = (const float*)d_in[1];
    const float* R_pred = (const float*)d_in[2];
    const float* t_pred = (const float*)d_in[3];
    const float* R_true = (const float*)d_in[4];
    const float* t_true = (const float*)d_in[5];
    const float* temp   = (const float*)d_in[6];
    float* out = (float*)d_out;

    hipMemsetAsync(out, 0, sizeof(float), stream);

    softfape_kernel<<<dim3(B_ * (N_ / ROWS)), BLOCK, 0, stream>>>(
        X_pred, X_true, R_pred, t_pred, R_true, t_true, temp, out);
}